// Round 1
// baseline (528.266 us; speedup 1.0000x reference)
//
#include <hip/hip_runtime.h>
#include <hip/hip_bf16.h>

#define N_NODES 100000
#define N_EDGES 1600000
#define DIM_IN 128
#define DIM_OUT 64

// ---------------- CSR build ----------------

__global__ void hist_kernel(const int* __restrict__ erow, int* __restrict__ cnt, int nE) {
    int e = blockIdx.x * 256 + threadIdx.x;
    if (e < nE) atomicAdd(&cnt[erow[e]], 1);
}

// Per-block inclusive scan over 1024 elements (256 threads x 4)
__global__ void scan1_kernel(const int* __restrict__ cnt, int* __restrict__ incl,
                             int* __restrict__ blockSums, int n) {
    __shared__ int sdata[256];
    int t = threadIdx.x;
    int base = blockIdx.x * 1024 + t * 4;
    int v[4];
    int s = 0;
#pragma unroll
    for (int i = 0; i < 4; ++i) {
        v[i] = (base + i < n) ? cnt[base + i] : 0;
        s += v[i];
    }
    sdata[t] = s;
    __syncthreads();
#pragma unroll
    for (int off = 1; off < 256; off <<= 1) {
        int x = sdata[t];
        int y = (t >= off) ? sdata[t - off] : 0;
        __syncthreads();
        sdata[t] = x + y;
        __syncthreads();
    }
    int run = sdata[t] - s;  // exclusive prefix for this thread
#pragma unroll
    for (int i = 0; i < 4; ++i) {
        run += v[i];
        if (base + i < n) incl[base + i] = run;
    }
    if (t == 255) blockSums[blockIdx.x] = sdata[255];
}

__global__ void scan2_kernel(const int* __restrict__ blockSums, int* __restrict__ blockOffs, int nb) {
    __shared__ int s[128];
    int t = threadIdx.x;  // 128 threads
    int v = (t < nb) ? blockSums[t] : 0;
    s[t] = v;
    __syncthreads();
#pragma unroll
    for (int off = 1; off < 128; off <<= 1) {
        int x = s[t];
        int y = (t >= off) ? s[t - off] : 0;
        __syncthreads();
        s[t] = x + y;
        __syncthreads();
    }
    if (t < nb) blockOffs[t] = s[t] - v;  // exclusive block offset
}

__global__ void scan3_kernel(int* __restrict__ row_ptr_incl, const int* __restrict__ cnt,
                             const int* __restrict__ blockOffs, int n, int total) {
    int i = blockIdx.x * 256 + threadIdx.x;
    if (i < n) {
        int incl = row_ptr_incl[i];
        row_ptr_incl[i] = incl - cnt[i] + blockOffs[i >> 10];  // exclusive global
    }
    if (i == 0) row_ptr_incl[n] = total;
}

__global__ void scatter_kernel(const int* __restrict__ erow, const int* __restrict__ ecol,
                               const float* __restrict__ eval, const int* __restrict__ row_ptr,
                               int* __restrict__ cnt2, int2* __restrict__ ep, int nE) {
    int e = blockIdx.x * 256 + threadIdx.x;
    if (e >= nE) return;
    int r = erow[e];
    int pos = row_ptr[r] + atomicAdd(&cnt2[r], 1);
    ep[pos] = make_int2(ecol[e], __float_as_int(eval[e]));
}

// ---------------- SpMM: one wave per row, float2 per lane (64*2 = 128 dims) ----------------

__global__ __launch_bounds__(256) void spmm_kernel(const int2* __restrict__ ep,
                                                   const int* __restrict__ row_ptr,
                                                   const float* __restrict__ X,
                                                   float* __restrict__ out) {
    int wave = threadIdx.x >> 6;
    int lane = threadIdx.x & 63;
    int r = blockIdx.x * 4 + wave;
    if (r >= N_NODES) return;
    int beg = row_ptr[r];
    int end = row_ptr[r + 1];
    float2 acc = make_float2(0.f, 0.f);
    int e = beg;
    for (; e + 1 < end; e += 2) {
        int2 cv0 = ep[e];
        int2 cv1 = ep[e + 1];
        float v0 = __int_as_float(cv0.y);
        float v1 = __int_as_float(cv1.y);
        const float2 x0 = *reinterpret_cast<const float2*>(X + (size_t)cv0.x * DIM_IN + lane * 2);
        const float2 x1 = *reinterpret_cast<const float2*>(X + (size_t)cv1.x * DIM_IN + lane * 2);
        acc.x += v0 * x0.x;
        acc.y += v0 * x0.y;
        acc.x += v1 * x1.x;
        acc.y += v1 * x1.y;
    }
    if (e < end) {
        int2 cv = ep[e];
        float v = __int_as_float(cv.y);
        const float2 x = *reinterpret_cast<const float2*>(X + (size_t)cv.x * DIM_IN + lane * 2);
        acc.x += v * x.x;
        acc.y += v * x.y;
    }
    *reinterpret_cast<float2*>(out + (size_t)r * DIM_IN + lane * 2) = acc;
}

// ---------------- GEMM + tanh: out[i,j] = tanh(sum_k A[i,k] * W[j,k]) ----------------
// A: [M,128] row-major, W: [NOUT,128] row-major. Tile: 64 rows x NOUT cols.
// 256 threads as 16x16: each thread 4 rows x (NOUT/16) cols. K staged in 2 halves of 64.

template <int NOUT>
__global__ __launch_bounds__(256) void gemm_tanh_kernel(const float* __restrict__ A,
                                                        const float* __restrict__ W,
                                                        float* __restrict__ out, int M) {
    constexpr int COLS = NOUT / 16;        // 8 (layer1) or 4 (layer2)
    constexpr int LDS_STRIDE = 65;         // pad: 2-way bank aliasing only (free)
    __shared__ float sA[64 * LDS_STRIDE];
    __shared__ float sW[NOUT * LDS_STRIDE];

    const int t = threadIdx.x;
    const int tr = t & 15;      // row group 0..15 (4 rows each)
    const int tc = t >> 4;      // col group 0..15 (COLS cols each)
    const int row0 = blockIdx.x * 64;

    float acc[4][COLS];
#pragma unroll
    for (int r = 0; r < 4; ++r)
#pragma unroll
        for (int c = 0; c < COLS; ++c) acc[r][c] = 0.f;

    for (int kh = 0; kh < 2; ++kh) {
        const int kbase = kh * 64;
        // stage A tile: 64 rows x 64 k
#pragma unroll
        for (int p = 0; p < 4; ++p) {
            int r = (t >> 4) + 16 * p;
            int c = (t & 15) * 4;
            int gr = row0 + r;
            float4 v = make_float4(0.f, 0.f, 0.f, 0.f);
            if (gr < M) v = *reinterpret_cast<const float4*>(A + (size_t)gr * DIM_IN + kbase + c);
            sA[r * LDS_STRIDE + c + 0] = v.x;
            sA[r * LDS_STRIDE + c + 1] = v.y;
            sA[r * LDS_STRIDE + c + 2] = v.z;
            sA[r * LDS_STRIDE + c + 3] = v.w;
        }
        // stage W tile: NOUT rows x 64 k
#pragma unroll
        for (int p = 0; p < NOUT / 16; ++p) {
            int r = (t >> 4) + 16 * p;
            int c = (t & 15) * 4;
            float4 v = *reinterpret_cast<const float4*>(W + (size_t)r * DIM_IN + kbase + c);
            sW[r * LDS_STRIDE + c + 0] = v.x;
            sW[r * LDS_STRIDE + c + 1] = v.y;
            sW[r * LDS_STRIDE + c + 2] = v.z;
            sW[r * LDS_STRIDE + c + 3] = v.w;
        }
        __syncthreads();
#pragma unroll 8
        for (int kk = 0; kk < 64; ++kk) {
            float a[4], w[COLS];
#pragma unroll
            for (int r = 0; r < 4; ++r) a[r] = sA[(tr * 4 + r) * LDS_STRIDE + kk];
#pragma unroll
            for (int c = 0; c < COLS; ++c) w[c] = sW[(tc * COLS + c) * LDS_STRIDE + kk];
#pragma unroll
            for (int r = 0; r < 4; ++r)
#pragma unroll
                for (int c = 0; c < COLS; ++c) acc[r][c] += a[r] * w[c];
        }
        __syncthreads();
    }

    // epilogue: tanh + store
#pragma unroll
    for (int r = 0; r < 4; ++r) {
        int gr = row0 + tr * 4 + r;
        if (gr >= M) continue;
#pragma unroll
        for (int c = 0; c < COLS; ++c) {
            out[(size_t)gr * NOUT + tc * COLS + c] = tanhf(acc[r][c]);
        }
    }
}

// ---------------- launch ----------------

extern "C" void kernel_launch(void* const* d_in, const int* in_sizes, int n_in,
                              void* d_out, int out_size, void* d_ws, size_t ws_size,
                              hipStream_t stream) {
    const float* X = (const float*)d_in[0];
    const float* W1 = (const float*)d_in[1];
    const float* W2 = (const float*)d_in[2];
    const float* evals = (const float*)d_in[3];
    const int* erow = (const int*)d_in[4];
    const int* ecol = (const int*)d_in[5];
    float* out = (float*)d_out;

    const int N = N_NODES;
    const int E = N_EDGES;

    // workspace layout (256B aligned)
    char* ws = (char*)d_ws;
    size_t off = 0;
    auto alloc = [&](size_t bytes) {
        size_t o = off;
        off = (off + bytes + 255) & ~(size_t)255;
        return o;
    };
    size_t o_cnt = alloc((size_t)N * 4);
    size_t o_cnt2 = alloc((size_t)N * 4);
    size_t zero_end = off;  // zero cnt + cnt2
    size_t o_rowptr = alloc((size_t)(N + 1) * 4);
    size_t o_bsums = alloc(128 * 4);
    size_t o_boffs = alloc(128 * 4);
    size_t o_ep = alloc((size_t)E * 8);
    size_t o_agg = alloc((size_t)N * DIM_IN * 4);
    size_t o_h = alloc((size_t)N * DIM_IN * 4);
    (void)ws_size;

    int* cnt = (int*)(ws + o_cnt);
    int* cnt2 = (int*)(ws + o_cnt2);
    int* row_ptr = (int*)(ws + o_rowptr);
    int* bsums = (int*)(ws + o_bsums);
    int* boffs = (int*)(ws + o_boffs);
    int2* ep = (int2*)(ws + o_ep);
    float* agg = (float*)(ws + o_agg);
    float* h = (float*)(ws + o_h);

    hipMemsetAsync(d_ws, 0, zero_end, stream);

    const int egrid = (E + 255) / 256;
    const int nscan = (N + 1023) / 1024;  // 98

    // CSR build
    hist_kernel<<<egrid, 256, 0, stream>>>(erow, cnt, E);
    scan1_kernel<<<nscan, 256, 0, stream>>>(cnt, row_ptr, bsums, N);
    scan2_kernel<<<1, 128, 0, stream>>>(bsums, boffs, nscan);
    scan3_kernel<<<(N + 255) / 256, 256, 0, stream>>>(row_ptr, cnt, boffs, N, E);
    scatter_kernel<<<egrid, 256, 0, stream>>>(erow, ecol, evals, row_ptr, cnt2, ep, E);

    const int spmm_grid = (N + 3) / 4;
    const int gemm_grid = (N + 63) / 64;

    // layer 1
    spmm_kernel<<<spmm_grid, 256, 0, stream>>>(ep, row_ptr, X, agg);
    gemm_tanh_kernel<128><<<gemm_grid, 256, 0, stream>>>(agg, W1, h, N);
    // layer 2 (reuse agg)
    spmm_kernel<<<spmm_grid, 256, 0, stream>>>(ep, row_ptr, h, agg);
    gemm_tanh_kernel<64><<<gemm_grid, 256, 0, stream>>>(agg, W2, out, N);
}

// Round 2
// 488.130 us; speedup vs baseline: 1.0822x; 1.0822x over previous
//
#include <hip/hip_runtime.h>
#include <hip/hip_bf16.h>

#define N_NODES 100000
#define N_EDGES 1600000
#define DIM_IN 128
#define DIM_OUT 64

// ---------------- CSR build ----------------

__global__ void hist_kernel(const int* __restrict__ erow, int* __restrict__ cnt, int nE) {
    int e = blockIdx.x * 256 + threadIdx.x;
    if (e < nE) atomicAdd(&cnt[erow[e]], 1);
}

// Per-block inclusive scan over 1024 elements (256 threads x 4)
__global__ void scan1_kernel(const int* __restrict__ cnt, int* __restrict__ incl,
                             int* __restrict__ blockSums, int n) {
    __shared__ int sdata[256];
    int t = threadIdx.x;
    int base = blockIdx.x * 1024 + t * 4;
    int v[4];
    int s = 0;
#pragma unroll
    for (int i = 0; i < 4; ++i) {
        v[i] = (base + i < n) ? cnt[base + i] : 0;
        s += v[i];
    }
    sdata[t] = s;
    __syncthreads();
#pragma unroll
    for (int off = 1; off < 256; off <<= 1) {
        int x = sdata[t];
        int y = (t >= off) ? sdata[t - off] : 0;
        __syncthreads();
        sdata[t] = x + y;
        __syncthreads();
    }
    int run = sdata[t] - s;  // exclusive prefix for this thread
#pragma unroll
    for (int i = 0; i < 4; ++i) {
        run += v[i];
        if (base + i < n) incl[base + i] = run;
    }
    if (t == 255) blockSums[blockIdx.x] = sdata[255];
}

__global__ void scan2_kernel(const int* __restrict__ blockSums, int* __restrict__ blockOffs, int nb) {
    __shared__ int s[128];
    int t = threadIdx.x;  // 128 threads
    int v = (t < nb) ? blockSums[t] : 0;
    s[t] = v;
    __syncthreads();
#pragma unroll
    for (int off = 1; off < 128; off <<= 1) {
        int x = s[t];
        int y = (t >= off) ? s[t - off] : 0;
        __syncthreads();
        s[t] = x + y;
        __syncthreads();
    }
    if (t < nb) blockOffs[t] = s[t] - v;  // exclusive block offset
}

__global__ void scan3_kernel(int* __restrict__ row_ptr_incl, const int* __restrict__ cnt,
                             const int* __restrict__ blockOffs, int n, int total) {
    int i = blockIdx.x * 256 + threadIdx.x;
    if (i < n) {
        int incl = row_ptr_incl[i];
        row_ptr_incl[i] = incl - cnt[i] + blockOffs[i >> 10];  // exclusive global
    }
    if (i == 0) row_ptr_incl[n] = total;
}

__global__ void scatter_kernel(const int* __restrict__ erow, const int* __restrict__ ecol,
                               const float* __restrict__ eval, const int* __restrict__ row_ptr,
                               int* __restrict__ cnt2, int2* __restrict__ ep, int nE) {
    int e = blockIdx.x * 256 + threadIdx.x;
    if (e >= nE) return;
    int r = erow[e];
    int pos = row_ptr[r] + atomicAdd(&cnt2[r], 1);
    ep[pos] = make_int2(ecol[e], __float_as_int(eval[e]));
}

// ---------------- SpMM 128-dim: one wave per row, float2 per lane ----------------

__global__ __launch_bounds__(256) void spmm_kernel(const int2* __restrict__ ep,
                                                   const int* __restrict__ row_ptr,
                                                   const float* __restrict__ X,
                                                   float* __restrict__ out) {
    int wave = threadIdx.x >> 6;
    int lane = threadIdx.x & 63;
    int r = blockIdx.x * 4 + wave;
    if (r >= N_NODES) return;
    int beg = row_ptr[r];
    int end = row_ptr[r + 1];
    float2 acc0 = make_float2(0.f, 0.f);
    float2 acc1 = make_float2(0.f, 0.f);
    int e = beg;
    for (; e + 3 < end; e += 4) {
        int2 cv0 = ep[e];
        int2 cv1 = ep[e + 1];
        int2 cv2 = ep[e + 2];
        int2 cv3 = ep[e + 3];
        const float2 x0 = *reinterpret_cast<const float2*>(X + (size_t)cv0.x * DIM_IN + lane * 2);
        const float2 x1 = *reinterpret_cast<const float2*>(X + (size_t)cv1.x * DIM_IN + lane * 2);
        const float2 x2 = *reinterpret_cast<const float2*>(X + (size_t)cv2.x * DIM_IN + lane * 2);
        const float2 x3 = *reinterpret_cast<const float2*>(X + (size_t)cv3.x * DIM_IN + lane * 2);
        float v0 = __int_as_float(cv0.y);
        float v1 = __int_as_float(cv1.y);
        float v2 = __int_as_float(cv2.y);
        float v3 = __int_as_float(cv3.y);
        acc0.x += v0 * x0.x; acc0.y += v0 * x0.y;
        acc1.x += v1 * x1.x; acc1.y += v1 * x1.y;
        acc0.x += v2 * x2.x; acc0.y += v2 * x2.y;
        acc1.x += v3 * x3.x; acc1.y += v3 * x3.y;
    }
    for (; e < end; ++e) {
        int2 cv = ep[e];
        float v = __int_as_float(cv.y);
        const float2 x = *reinterpret_cast<const float2*>(X + (size_t)cv.x * DIM_IN + lane * 2);
        acc0.x += v * x.x;
        acc0.y += v * x.y;
    }
    acc0.x += acc1.x;
    acc0.y += acc1.y;
    *reinterpret_cast<float2*>(out + (size_t)r * DIM_IN + lane * 2) = acc0;
}

// ---------------- SpMM 64-dim with tanh epilogue: one wave per row, 1 float/lane --------

__global__ __launch_bounds__(256) void spmm64_tanh_kernel(const int2* __restrict__ ep,
                                                          const int* __restrict__ row_ptr,
                                                          const float* __restrict__ P,
                                                          float* __restrict__ out) {
    int wave = threadIdx.x >> 6;
    int lane = threadIdx.x & 63;
    int r = blockIdx.x * 4 + wave;
    if (r >= N_NODES) return;
    int beg = row_ptr[r];
    int end = row_ptr[r + 1];
    float acc0 = 0.f, acc1 = 0.f;
    int e = beg;
    for (; e + 3 < end; e += 4) {
        int2 cv0 = ep[e];
        int2 cv1 = ep[e + 1];
        int2 cv2 = ep[e + 2];
        int2 cv3 = ep[e + 3];
        float x0 = P[(size_t)cv0.x * DIM_OUT + lane];
        float x1 = P[(size_t)cv1.x * DIM_OUT + lane];
        float x2 = P[(size_t)cv2.x * DIM_OUT + lane];
        float x3 = P[(size_t)cv3.x * DIM_OUT + lane];
        acc0 += __int_as_float(cv0.y) * x0;
        acc1 += __int_as_float(cv1.y) * x1;
        acc0 += __int_as_float(cv2.y) * x2;
        acc1 += __int_as_float(cv3.y) * x3;
    }
    for (; e < end; ++e) {
        int2 cv = ep[e];
        acc0 += __int_as_float(cv.y) * P[(size_t)cv.x * DIM_OUT + lane];
    }
    out[(size_t)r * DIM_OUT + lane] = tanhf(acc0 + acc1);
}

// ---------------- GEMM: out[i,j] = (tanh?)(sum_k A[i,k] * W[j,k]) ----------------
// Block tile: 128 rows x NOUT cols. 256 threads as 16(tr) x 16(tc); per thread 8 rows x
// NOUT/16 cols. K staged in tiles of 32 with XOR swizzle (col4 ^= (row>>3)&7) so inner
// ds_read_b128 along k is 2-way (A, free) / conflict-free (W).

template <int NOUT, bool TANH>
__global__ __launch_bounds__(256) void gemm_kernel(const float* __restrict__ A,
                                                   const float* __restrict__ W,
                                                   float* __restrict__ out, int M) {
    constexpr int CPT = NOUT / 16;  // 8 (layer1) or 4 (layer2)
    constexpr int BK = 32;
    __shared__ __align__(16) float sA[128 * BK];
    __shared__ __align__(16) float sW[NOUT * BK];

    const int t = threadIdx.x;
    const int tr = t & 15;
    const int tc = t >> 4;
    const int row0 = blockIdx.x * 128;

    float acc[8][CPT];
#pragma unroll
    for (int r = 0; r < 8; ++r)
#pragma unroll
        for (int c = 0; c < CPT; ++c) acc[r][c] = 0.f;

    for (int kb = 0; kb < DIM_IN / BK; ++kb) {
        // stage A: 128 rows x 32 k = 1024 float4
#pragma unroll
        for (int p = 0; p < 4; ++p) {
            int fid = p * 256 + t;
            int row = fid >> 3;
            int col4 = fid & 7;
            int gr = row0 + row;
            float4 v = make_float4(0.f, 0.f, 0.f, 0.f);
            if (gr < M) v = *reinterpret_cast<const float4*>(A + (size_t)gr * DIM_IN + kb * BK + col4 * 4);
            int sw = col4 ^ ((row >> 3) & 7);
            *reinterpret_cast<float4*>(sA + row * BK + sw * 4) = v;
        }
        // stage W: NOUT rows x 32 k
#pragma unroll
        for (int p = 0; p < NOUT / 32; ++p) {
            int fid = p * 256 + t;
            int row = fid >> 3;
            int col4 = fid & 7;
            float4 v = *reinterpret_cast<const float4*>(W + (size_t)row * DIM_IN + kb * BK + col4 * 4);
            int sw = col4 ^ ((row >> 3) & 7);
            *reinterpret_cast<float4*>(sW + row * BK + sw * 4) = v;
        }
        __syncthreads();
#pragma unroll
        for (int k4 = 0; k4 < 8; ++k4) {
            float4 a4[8];
            const int swa = (k4 ^ (tr & 7)) << 2;
#pragma unroll
            for (int r = 0; r < 8; ++r)
                a4[r] = *reinterpret_cast<const float4*>(sA + (tr * 8 + r) * BK + swa);
            float4 w4[CPT];
#pragma unroll
            for (int c = 0; c < CPT; ++c) {
                int wrow = tc * CPT + c;
                int sww = (k4 ^ ((wrow >> 3) & 7)) << 2;
                w4[c] = *reinterpret_cast<const float4*>(sW + wrow * BK + sww);
            }
#pragma unroll
            for (int r = 0; r < 8; ++r)
#pragma unroll
                for (int c = 0; c < CPT; ++c) {
                    acc[r][c] += a4[r].x * w4[c].x;
                    acc[r][c] += a4[r].y * w4[c].y;
                    acc[r][c] += a4[r].z * w4[c].z;
                    acc[r][c] += a4[r].w * w4[c].w;
                }
        }
        __syncthreads();
    }

    // epilogue: optional tanh + vectorized store (per-thread cols are contiguous)
#pragma unroll
    for (int r = 0; r < 8; ++r) {
        int gr = row0 + tr * 8 + r;
        if (gr >= M) continue;
#pragma unroll
        for (int c4 = 0; c4 < CPT / 4; ++c4) {
            float4 v;
            v.x = TANH ? tanhf(acc[r][c4 * 4 + 0]) : acc[r][c4 * 4 + 0];
            v.y = TANH ? tanhf(acc[r][c4 * 4 + 1]) : acc[r][c4 * 4 + 1];
            v.z = TANH ? tanhf(acc[r][c4 * 4 + 2]) : acc[r][c4 * 4 + 2];
            v.w = TANH ? tanhf(acc[r][c4 * 4 + 3]) : acc[r][c4 * 4 + 3];
            *reinterpret_cast<float4*>(out + (size_t)gr * NOUT + tc * CPT + c4 * 4) = v;
        }
    }
}

// ---------------- launch ----------------

extern "C" void kernel_launch(void* const* d_in, const int* in_sizes, int n_in,
                              void* d_out, int out_size, void* d_ws, size_t ws_size,
                              hipStream_t stream) {
    const float* X = (const float*)d_in[0];
    const float* W1 = (const float*)d_in[1];
    const float* W2 = (const float*)d_in[2];
    const float* evals = (const float*)d_in[3];
    const int* erow = (const int*)d_in[4];
    const int* ecol = (const int*)d_in[5];
    float* out = (float*)d_out;

    const int N = N_NODES;
    const int E = N_EDGES;

    // workspace layout (256B aligned)
    char* ws = (char*)d_ws;
    size_t off = 0;
    auto alloc = [&](size_t bytes) {
        size_t o = off;
        off = (off + bytes + 255) & ~(size_t)255;
        return o;
    };
    size_t o_cnt = alloc((size_t)N * 4);
    size_t o_cnt2 = alloc((size_t)N * 4);
    size_t zero_end = off;  // zero cnt + cnt2
    size_t o_rowptr = alloc((size_t)(N + 1) * 4);
    size_t o_bsums = alloc(128 * 4);
    size_t o_boffs = alloc(128 * 4);
    size_t o_ep = alloc((size_t)E * 8);
    size_t o_agg = alloc((size_t)N * DIM_IN * 4);  // also reused as P [N,64]
    size_t o_h = alloc((size_t)N * DIM_IN * 4);
    (void)ws_size;

    int* cnt = (int*)(ws + o_cnt);
    int* cnt2 = (int*)(ws + o_cnt2);
    int* row_ptr = (int*)(ws + o_rowptr);
    int* bsums = (int*)(ws + o_bsums);
    int* boffs = (int*)(ws + o_boffs);
    int2* ep = (int2*)(ws + o_ep);
    float* agg = (float*)(ws + o_agg);
    float* h = (float*)(ws + o_h);
    float* p = agg;  // [N,64], reuses agg after layer-1 GEMM consumed it

    hipMemsetAsync(d_ws, 0, zero_end, stream);

    const int egrid = (E + 255) / 256;
    const int nscan = (N + 1023) / 1024;  // 98

    // CSR build
    hist_kernel<<<egrid, 256, 0, stream>>>(erow, cnt, E);
    scan1_kernel<<<nscan, 256, 0, stream>>>(cnt, row_ptr, bsums, N);
    scan2_kernel<<<1, 128, 0, stream>>>(bsums, boffs, nscan);
    scan3_kernel<<<(N + 255) / 256, 256, 0, stream>>>(row_ptr, cnt, boffs, N, E);
    scatter_kernel<<<egrid, 256, 0, stream>>>(erow, ecol, evals, row_ptr, cnt2, ep, E);

    const int spmm_grid = (N + 3) / 4;
    const int gemm_grid = (N + 127) / 128;

    // layer 1: agg = A*X ; h = tanh(agg @ W1^T)
    spmm_kernel<<<spmm_grid, 256, 0, stream>>>(ep, row_ptr, X, agg);
    gemm_kernel<128, true><<<gemm_grid, 256, 0, stream>>>(agg, W1, h, N);
    // layer 2 (reordered): p = h @ W2^T ; out = tanh(A*p)
    gemm_kernel<64, false><<<gemm_grid, 256, 0, stream>>>(h, W2, p, N);
    spmm64_tanh_kernel<<<spmm_grid, 256, 0, stream>>>(ep, row_ptr, p, out);
}

// Round 4
// 457.450 us; speedup vs baseline: 1.1548x; 1.0671x over previous
//
#include <hip/hip_runtime.h>
#include <hip/hip_bf16.h>
#include <hip/hip_fp16.h>

#define N_NODES 100000
#define N_EDGES 1600000
#define DIM_IN 128
#define DIM_OUT 64

typedef unsigned int uint;
typedef unsigned short ushort;

__device__ inline ushort f2h(float f) {
    __half h = __float2half(f);  // round-to-nearest-even
    return *reinterpret_cast<ushort*>(&h);
}

// ---------------- CSR build ----------------

__global__ void hist_kernel(const int* __restrict__ erow, int* __restrict__ cnt, int nE) {
    int e = blockIdx.x * 256 + threadIdx.x;
    if (e < nE) atomicAdd(&cnt[erow[e]], 1);
}

// Per-block inclusive scan over 1024 elements (256 threads x 4)
__global__ void scan1_kernel(const int* __restrict__ cnt, int* __restrict__ incl,
                             int* __restrict__ blockSums, int n) {
    __shared__ int sdata[256];
    int t = threadIdx.x;
    int base = blockIdx.x * 1024 + t * 4;
    int v[4];
    int s = 0;
#pragma unroll
    for (int i = 0; i < 4; ++i) {
        v[i] = (base + i < n) ? cnt[base + i] : 0;
        s += v[i];
    }
    sdata[t] = s;
    __syncthreads();
#pragma unroll
    for (int off = 1; off < 256; off <<= 1) {
        int x = sdata[t];
        int y = (t >= off) ? sdata[t - off] : 0;
        __syncthreads();
        sdata[t] = x + y;
        __syncthreads();
    }
    int run = sdata[t] - s;  // exclusive prefix for this thread
#pragma unroll
    for (int i = 0; i < 4; ++i) {
        run += v[i];
        if (base + i < n) incl[base + i] = run;
    }
    if (t == 255) blockSums[blockIdx.x] = sdata[255];
}

__global__ void scan2_kernel(const int* __restrict__ blockSums, int* __restrict__ blockOffs, int nb) {
    __shared__ int s[128];
    int t = threadIdx.x;  // 128 threads
    int v = (t < nb) ? blockSums[t] : 0;
    s[t] = v;
    __syncthreads();
#pragma unroll
    for (int off = 1; off < 128; off <<= 1) {
        int x = s[t];
        int y = (t >= off) ? s[t - off] : 0;
        __syncthreads();
        s[t] = x + y;
        __syncthreads();
    }
    if (t < nb) blockOffs[t] = s[t] - v;  // exclusive block offset
}

__global__ void scan3_kernel(int* __restrict__ row_ptr_incl, const int* __restrict__ cnt,
                             const int* __restrict__ blockOffs, int n, int total) {
    int i = blockIdx.x * 256 + threadIdx.x;
    if (i < n) {
        int incl = row_ptr_incl[i];
        row_ptr_incl[i] = incl - cnt[i] + blockOffs[i >> 10];  // exclusive global
    }
    if (i == 0) row_ptr_incl[n] = total;
}

__global__ void scatter_kernel(const int* __restrict__ erow, const int* __restrict__ ecol,
                               const float* __restrict__ eval, const int* __restrict__ row_ptr,
                               int* __restrict__ cnt2, int2* __restrict__ ep, int nE) {
    int e = blockIdx.x * 256 + threadIdx.x;
    if (e >= nE) return;
    int r = erow[e];
    int pos = row_ptr[r] + atomicAdd(&cnt2[r], 1);
    ep[pos] = make_int2(ecol[e], __float_as_int(eval[e]));
}

// ---------------- f32 -> f16 conversion (8 elems/thread) ----------------

__global__ __launch_bounds__(256) void cvt_f16_kernel(const float* __restrict__ in,
                                                      uint* __restrict__ outp, int n8) {
    int i = blockIdx.x * 256 + threadIdx.x;
    if (i >= n8) return;
    const float4* in4 = reinterpret_cast<const float4*>(in) + (size_t)i * 2;
    float4 a = in4[0];
    float4 b = in4[1];
    uint4 o;
    o.x = (uint)f2h(a.x) | ((uint)f2h(a.y) << 16);
    o.y = (uint)f2h(a.z) | ((uint)f2h(a.w) << 16);
    o.z = (uint)f2h(b.x) | ((uint)f2h(b.y) << 16);
    o.w = (uint)f2h(b.z) | ((uint)f2h(b.w) << 16);
    reinterpret_cast<uint4*>(outp)[i] = o;
}

// ---------------- SpMM 128-dim f16 gather: one wave per row, 2 dims/lane ----------------

__global__ __launch_bounds__(256) void spmm_f16_kernel(const int2* __restrict__ ep,
                                                       const int* __restrict__ row_ptr,
                                                       const uint* __restrict__ Xh,
                                                       float* __restrict__ out) {
    int wave = threadIdx.x >> 6;
    int lane = threadIdx.x & 63;
    int r = blockIdx.x * 4 + wave;
    if (r >= N_NODES) return;
    int beg = row_ptr[r];
    int end = row_ptr[r + 1];
    float a0x = 0.f, a0y = 0.f, a1x = 0.f, a1y = 0.f;
    int e = beg;
    for (; e + 7 < end; e += 8) {
        int2 cv[8];
        uint xu[8];
#pragma unroll
        for (int i = 0; i < 8; ++i) cv[i] = ep[e + i];
#pragma unroll
        for (int i = 0; i < 8; ++i) xu[i] = Xh[(size_t)cv[i].x * 64 + lane];
#pragma unroll
        for (int i = 0; i < 8; ++i) {
            float v = __int_as_float(cv[i].y);
            __half2 h2 = *reinterpret_cast<__half2*>(&xu[i]);
            float2 f = __half22float2(h2);
            if (i & 1) { a1x += v * f.x; a1y += v * f.y; }
            else       { a0x += v * f.x; a0y += v * f.y; }
        }
    }
    for (; e < end; ++e) {
        int2 cv = ep[e];
        float v = __int_as_float(cv.y);
        uint xu = Xh[(size_t)cv.x * 64 + lane];
        __half2 h2 = *reinterpret_cast<__half2*>(&xu);
        float2 f = __half22float2(h2);
        a0x += v * f.x;
        a0y += v * f.y;
    }
    float2 o = make_float2(a0x + a1x, a0y + a1y);
    *reinterpret_cast<float2*>(out + (size_t)r * DIM_IN + lane * 2) = o;
}

// ---------------- SpMM 64-dim f16 gather + tanh: one wave per row, 1 dim/lane ----------

__global__ __launch_bounds__(256) void spmm64_f16_tanh_kernel(const int2* __restrict__ ep,
                                                              const int* __restrict__ row_ptr,
                                                              const ushort* __restrict__ Ph,
                                                              float* __restrict__ out) {
    int wave = threadIdx.x >> 6;
    int lane = threadIdx.x & 63;
    int r = blockIdx.x * 4 + wave;
    if (r >= N_NODES) return;
    int beg = row_ptr[r];
    int end = row_ptr[r + 1];
    float acc0 = 0.f, acc1 = 0.f;
    int e = beg;
    for (; e + 7 < end; e += 8) {
        int2 cv[8];
        ushort xu[8];
#pragma unroll
        for (int i = 0; i < 8; ++i) cv[i] = ep[e + i];
#pragma unroll
        for (int i = 0; i < 8; ++i) xu[i] = Ph[(size_t)cv[i].x * 64 + lane];
#pragma unroll
        for (int i = 0; i < 8; ++i) {
            float v = __int_as_float(cv[i].y);
            __half h = *reinterpret_cast<__half*>(&xu[i]);
            float x = __half2float(h);
            if (i & 1) acc1 += v * x;
            else       acc0 += v * x;
        }
    }
    for (; e < end; ++e) {
        int2 cv = ep[e];
        ushort u = Ph[(size_t)cv.x * 64 + lane];
        __half h = *reinterpret_cast<__half*>(&u);
        acc0 += __int_as_float(cv.y) * __half2float(h);
    }
    out[(size_t)r * DIM_OUT + lane] = tanhf(acc0 + acc1);
}

// ---------------- GEMM: out[i,j] = (tanh?)(sum_k A[i,k] * W[j,k]) ----------------
// Block tile: 128 rows x NOUT cols. 256 threads as 16(tr) x 16(tc); per thread 8 rows x
// NOUT/16 cols. K staged in tiles of 32 with XOR swizzle (col4 ^= (row>>3)&7) so inner
// ds_read_b128 along k is 2-way (A, free) / conflict-free (W).

template <int NOUT, bool TANH, bool F16OUT>
__global__ __launch_bounds__(256) void gemm_kernel(const float* __restrict__ A,
                                                   const float* __restrict__ W,
                                                   void* __restrict__ out_v, int M) {
    constexpr int CPT = NOUT / 16;  // 8 (layer1) or 4 (layer2)
    constexpr int BK = 32;
    __shared__ __align__(16) float sA[128 * BK];
    __shared__ __align__(16) float sW[NOUT * BK];

    const int t = threadIdx.x;
    const int tr = t & 15;
    const int tc = t >> 4;
    const int row0 = blockIdx.x * 128;

    float acc[8][CPT];
#pragma unroll
    for (int r = 0; r < 8; ++r)
#pragma unroll
        for (int c = 0; c < CPT; ++c) acc[r][c] = 0.f;

    for (int kb = 0; kb < DIM_IN / BK; ++kb) {
        // stage A: 128 rows x 32 k = 1024 float4
#pragma unroll
        for (int p = 0; p < 4; ++p) {
            int fid = p * 256 + t;
            int row = fid >> 3;
            int col4 = fid & 7;
            int gr = row0 + row;
            float4 v = make_float4(0.f, 0.f, 0.f, 0.f);
            if (gr < M) v = *reinterpret_cast<const float4*>(A + (size_t)gr * DIM_IN + kb * BK + col4 * 4);
            int sw = col4 ^ ((row >> 3) & 7);
            *reinterpret_cast<float4*>(sA + row * BK + sw * 4) = v;
        }
        // stage W: NOUT rows x 32 k
#pragma unroll
        for (int p = 0; p < NOUT / 32; ++p) {
            int fid = p * 256 + t;
            int row = fid >> 3;
            int col4 = fid & 7;
            float4 v = *reinterpret_cast<const float4*>(W + (size_t)row * DIM_IN + kb * BK + col4 * 4);
            int sw = col4 ^ ((row >> 3) & 7);
            *reinterpret_cast<float4*>(sW + row * BK + sw * 4) = v;
        }
        __syncthreads();
#pragma unroll
        for (int k4 = 0; k4 < 8; ++k4) {
            float4 a4[8];
            const int swa = (k4 ^ (tr & 7)) << 2;
#pragma unroll
            for (int r = 0; r < 8; ++r)
                a4[r] = *reinterpret_cast<const float4*>(sA + (tr * 8 + r) * BK + swa);
            float4 w4[CPT];
#pragma unroll
            for (int c = 0; c < CPT; ++c) {
                int wrow = tc * CPT + c;
                int sww = (k4 ^ ((wrow >> 3) & 7)) << 2;
                w4[c] = *reinterpret_cast<const float4*>(sW + wrow * BK + sww);
            }
#pragma unroll
            for (int r = 0; r < 8; ++r)
#pragma unroll
                for (int c = 0; c < CPT; ++c) {
                    acc[r][c] += a4[r].x * w4[c].x;
                    acc[r][c] += a4[r].y * w4[c].y;
                    acc[r][c] += a4[r].z * w4[c].z;
                    acc[r][c] += a4[r].w * w4[c].w;
                }
        }
        __syncthreads();
    }

    // epilogue
#pragma unroll
    for (int r = 0; r < 8; ++r) {
        int gr = row0 + tr * 8 + r;
        if (gr >= M) continue;
        if (F16OUT) {
            ushort u[CPT];
#pragma unroll
            for (int c = 0; c < CPT; ++c)
                u[c] = f2h(TANH ? tanhf(acc[r][c]) : acc[r][c]);
            if (CPT == 4) {
                uint2 s;
                s.x = (uint)u[0] | ((uint)u[1] << 16);
                s.y = (uint)u[2] | ((uint)u[3] << 16);
                *reinterpret_cast<uint2*>((ushort*)out_v + (size_t)gr * NOUT + tc * CPT) = s;
            } else {
#pragma unroll
                for (int c = 0; c < CPT; ++c)
                    ((ushort*)out_v)[(size_t)gr * NOUT + tc * CPT + c] = u[c];
            }
        } else {
            float* out = (float*)out_v;
#pragma unroll
            for (int c4 = 0; c4 < CPT / 4; ++c4) {
                float4 v;
                v.x = TANH ? tanhf(acc[r][c4 * 4 + 0]) : acc[r][c4 * 4 + 0];
                v.y = TANH ? tanhf(acc[r][c4 * 4 + 1]) : acc[r][c4 * 4 + 1];
                v.z = TANH ? tanhf(acc[r][c4 * 4 + 2]) : acc[r][c4 * 4 + 2];
                v.w = TANH ? tanhf(acc[r][c4 * 4 + 3]) : acc[r][c4 * 4 + 3];
                *reinterpret_cast<float4*>(out + (size_t)gr * NOUT + tc * CPT + c4 * 4) = v;
            }
        }
    }
}

// ---------------- launch ----------------

extern "C" void kernel_launch(void* const* d_in, const int* in_sizes, int n_in,
                              void* d_out, int out_size, void* d_ws, size_t ws_size,
                              hipStream_t stream) {
    const float* X = (const float*)d_in[0];
    const float* W1 = (const float*)d_in[1];
    const float* W2 = (const float*)d_in[2];
    const float* evals = (const float*)d_in[3];
    const int* erow = (const int*)d_in[4];
    const int* ecol = (const int*)d_in[5];
    float* out = (float*)d_out;

    const int N = N_NODES;
    const int E = N_EDGES;

    // workspace layout (256B aligned)
    char* ws = (char*)d_ws;
    size_t off = 0;
    auto alloc = [&](size_t bytes) {
        size_t o = off;
        off = (off + bytes + 255) & ~(size_t)255;
        return o;
    };
    size_t o_cnt = alloc((size_t)N * 4);
    size_t o_cnt2 = alloc((size_t)N * 4);
    size_t zero_end = off;  // zero cnt + cnt2
    size_t o_rowptr = alloc((size_t)(N + 1) * 4);
    size_t o_bsums = alloc(128 * 4);
    size_t o_boffs = alloc(128 * 4);
    size_t o_ep = alloc((size_t)E * 8);
    size_t o_agg = alloc((size_t)N * DIM_IN * 4);  // agg f32 [N,128]; later reused as p f16 [N,64]
    size_t o_h = alloc((size_t)N * DIM_IN * 4);    // h f32 [N,128]; first reused as Xh f16 [N,128]
    (void)ws_size;

    int* cnt = (int*)(ws + o_cnt);
    int* cnt2 = (int*)(ws + o_cnt2);
    int* row_ptr = (int*)(ws + o_rowptr);
    int* bsums = (int*)(ws + o_bsums);
    int* boffs = (int*)(ws + o_boffs);
    int2* ep = (int2*)(ws + o_ep);
    float* agg = (float*)(ws + o_agg);
    float* h = (float*)(ws + o_h);
    uint* Xh = (uint*)(ws + o_h);      // [N,128] f16 (25.6MB), dead before gemm1 writes h
    ushort* p = (ushort*)(ws + o_agg); // [N,64] f16, agg dead after gemm1 reads it

    hipMemsetAsync(d_ws, 0, zero_end, stream);

    const int egrid = (E + 255) / 256;
    const int nscan = (N + 1023) / 1024;  // 98

    // X -> f16 (independent of CSR build; issue first)
    const int ncvt = N * DIM_IN / 8;  // 1.6M
    cvt_f16_kernel<<<(ncvt + 255) / 256, 256, 0, stream>>>(X, Xh, ncvt);

    // CSR build
    hist_kernel<<<egrid, 256, 0, stream>>>(erow, cnt, E);
    scan1_kernel<<<nscan, 256, 0, stream>>>(cnt, row_ptr, bsums, N);
    scan2_kernel<<<1, 128, 0, stream>>>(bsums, boffs, nscan);
    scan3_kernel<<<(N + 255) / 256, 256, 0, stream>>>(row_ptr, cnt, boffs, N, E);
    scatter_kernel<<<egrid, 256, 0, stream>>>(erow, ecol, evals, row_ptr, cnt2, ep, E);

    const int spmm_grid = (N + 3) / 4;
    const int gemm_grid = (N + 127) / 128;

    // layer 1: agg = A*Xh ; h = tanh(agg @ W1^T)
    spmm_f16_kernel<<<spmm_grid, 256, 0, stream>>>(ep, row_ptr, Xh, agg);
    gemm_kernel<128, true, false><<<gemm_grid, 256, 0, stream>>>(agg, W1, h, N);
    // layer 2 (reordered): p = f16(h @ W2^T) ; out = tanh(A*p)
    gemm_kernel<64, false, true><<<gemm_grid, 256, 0, stream>>>(h, W2, p, N);
    spmm64_f16_tanh_kernel<<<spmm_grid, 256, 0, stream>>>(ep, row_ptr, p, out);
}

// Round 5
// 327.937 us; speedup vs baseline: 1.6109x; 1.3949x over previous
//
#include <hip/hip_runtime.h>
#include <hip/hip_bf16.h>
#include <hip/hip_fp16.h>

#define N_NODES 100000
#define N_EDGES 1600000
#define DIM_IN 128
#define DIM_OUT 64

#define NB 391      // coarse buckets: row >> 8 (256 rows each; last has 160)
#define NCHUNK 391  // edge chunks
#define CHUNK 4096  // edges per chunk (NCHUNK*CHUNK >= N_EDGES)
#define BCAP 5120   // max edges per bucket (mean 4092, sd ~64 -> +16 sigma)

typedef unsigned int uint;
typedef unsigned short ushort;

__device__ inline ushort f2h(float f) {
    __half h = __float2half(f);  // round-to-nearest-even
    return *reinterpret_cast<ushort*>(&h);
}

// ---------------- CSR build: deterministic two-level counting sort ----------------
// No global atomics, no random single-edge global writes.

// A: per-chunk histogram over coarse buckets. counts[b * NCHUNK + c]
__global__ __launch_bounds__(256) void chunk_hist_kernel(const int* __restrict__ erow,
                                                         int* __restrict__ counts, int E) {
    __shared__ int hist[NB];
    const int t = threadIdx.x, c = blockIdx.x;
    for (int b = t; b < NB; b += 256) hist[b] = 0;
    __syncthreads();
    const int eb = c * CHUNK;
#pragma unroll
    for (int i = 0; i < CHUNK / 256; ++i) {
        int e = eb + i * 256 + t;
        if (e < E) atomicAdd(&hist[erow[e] >> 8], 1);
    }
    __syncthreads();
    for (int b = t; b < NB; b += 256) counts[b * NCHUNK + c] = hist[b];
}

// B1: per-bucket exclusive scan over chunks -> offnb[b][c]; tot[b] = bucket size
__global__ __launch_bounds__(512) void bucket_scan_kernel(const int* __restrict__ counts,
                                                          int* __restrict__ offnb,
                                                          int* __restrict__ tot) {
    __shared__ int s[512];
    const int b = blockIdx.x, t = threadIdx.x;
    int v = (t < NCHUNK) ? counts[b * NCHUNK + t] : 0;
    s[t] = v;
    __syncthreads();
#pragma unroll
    for (int o = 1; o < 512; o <<= 1) {
        int x = s[t];
        int y = (t >= o) ? s[t - o] : 0;
        __syncthreads();
        s[t] = x + y;
        __syncthreads();
    }
    if (t < NCHUNK) offnb[b * NCHUNK + t] = s[t] - v;
    if (t == 511) tot[b] = s[511];
}

// B2: exclusive scan over buckets -> bbase[0..NB], bbase[NB] = E
__global__ __launch_bounds__(512) void base_scan_kernel(const int* __restrict__ tot,
                                                        int* __restrict__ bbase) {
    __shared__ int s[512];
    const int t = threadIdx.x;
    int v = (t < NB) ? tot[t] : 0;
    s[t] = v;
    __syncthreads();
#pragma unroll
    for (int o = 1; o < 512; o <<= 1) {
        int x = s[t];
        int y = (t >= o) ? s[t - o] : 0;
        __syncthreads();
        s[t] = x + y;
        __syncthreads();
    }
    if (t < NB) bbase[t] = s[t] - v;
    if (t == 511) bbase[NB] = s[511];
}

// C: coarse scatter. Each chunk reorders its edges bucket-major in LDS, then writes
// each (chunk,bucket) segment contiguously. key = (row&255)<<17 | col ; val separate.
__global__ __launch_bounds__(512) void coarse_scatter_kernel(const int* __restrict__ erow,
                                                             const int* __restrict__ ecol,
                                                             const float* __restrict__ eval,
                                                             const int* __restrict__ offnb,
                                                             const int* __restrict__ bbase,
                                                             uint* __restrict__ keyOut,
                                                             float* __restrict__ valOut, int E) {
    __shared__ int hist[NB];
    __shared__ int segOff[NB];    // global start of this chunk's segment in bucket b
    __shared__ int localOff[NB];  // exclusive scan of hist
    __shared__ int sc[512];
    __shared__ int idxL[CHUNK];
    __shared__ int gaddrL[CHUNK];

    const int t = threadIdx.x, c = blockIdx.x;
    for (int b = t; b < NB; b += 512) {
        hist[b] = 0;
        segOff[b] = bbase[b] + offnb[b * NCHUNK + c];
    }
    __syncthreads();
    const int eb = c * CHUNK;
    uint bq[CHUNK / 512];  // b<<16 | local rank
#pragma unroll
    for (int i = 0; i < CHUNK / 512; ++i) {
        int e = eb + i * 512 + t;
        if (e < E) {
            int b = erow[e] >> 8;
            int q = atomicAdd(&hist[b], 1);
            bq[i] = ((uint)b << 16) | (uint)q;
        } else {
            bq[i] = 0xFFFFFFFFu;
        }
    }
    __syncthreads();
    // exclusive scan of hist (NB <= 512)
    int v = (t < NB) ? hist[t] : 0;
    sc[t] = v;
    __syncthreads();
#pragma unroll
    for (int o = 1; o < 512; o <<= 1) {
        int x = sc[t];
        int y = (t >= o) ? sc[t - o] : 0;
        __syncthreads();
        sc[t] = x + y;
        __syncthreads();
    }
    if (t < NB) localOff[t] = sc[t] - v;
    __syncthreads();
#pragma unroll
    for (int i = 0; i < CHUNK / 512; ++i) {
        if (bq[i] != 0xFFFFFFFFu) {
            int b = bq[i] >> 16;
            int q = bq[i] & 0xFFFF;
            int s = localOff[b] + q;
            idxL[s] = eb + i * 512 + t;
            gaddrL[s] = segOff[b] + q;
        }
    }
    __syncthreads();
    const int m = min(CHUNK, E - eb);
    for (int s = t; s < m; s += 512) {
        int e = idxL[s];
        int g = gaddrL[s];
        keyOut[g] = ((uint)(erow[e] & 255) << 17) | (uint)ecol[e];
        valOut[g] = eval[e];
    }
}

// D: fine counting sort within each bucket (256 rows) -> final ep (col,val) + row_ptr
__global__ __launch_bounds__(256) void fine_sort_kernel(const uint* __restrict__ keyOut,
                                                        const float* __restrict__ valOut,
                                                        const int* __restrict__ bbase,
                                                        int* __restrict__ row_ptr,
                                                        int2* __restrict__ ep) {
    __shared__ uint keyL[BCAP];
    __shared__ int hist[256];
    __shared__ int offs[256];
    const int b = blockIdx.x, t = threadIdx.x;
    const int s0 = bbase[b], s1 = bbase[b + 1];
    const int m = min(s1 - s0, BCAP);
    hist[t] = 0;
    __syncthreads();
    for (int j = t; j < m; j += 256) {
        uint k = keyOut[s0 + j];
        keyL[j] = k;
        atomicAdd(&hist[k >> 17], 1);
    }
    __syncthreads();
    int v = hist[t];
    offs[t] = v;
    __syncthreads();
#pragma unroll
    for (int o = 1; o < 256; o <<= 1) {
        int x = offs[t];
        int y = (t >= o) ? offs[t - o] : 0;
        __syncthreads();
        offs[t] = x + y;
        __syncthreads();
    }
    int excl = offs[t] - v;
    int row = b * 256 + t;
    if (row < N_NODES) row_ptr[row] = s0 + excl;
    if (b == NB - 1 && t == 0) row_ptr[N_NODES] = s1;
    hist[t] = excl;  // running placement cursor
    __syncthreads();
    for (int j = t; j < m; j += 256) {
        uint k = keyL[j];
        int pos = atomicAdd(&hist[k >> 17], 1);
        float vv = valOut[s0 + j];
        ep[s0 + pos] = make_int2((int)(k & 0x1FFFFu), __float_as_int(vv));
    }
}

// ---------------- f32 -> f16 conversion (8 elems/thread) ----------------

__global__ __launch_bounds__(256) void cvt_f16_kernel(const float* __restrict__ in,
                                                      uint* __restrict__ outp, int n8) {
    int i = blockIdx.x * 256 + threadIdx.x;
    if (i >= n8) return;
    const float4* in4 = reinterpret_cast<const float4*>(in) + (size_t)i * 2;
    float4 a = in4[0];
    float4 b = in4[1];
    uint4 o;
    o.x = (uint)f2h(a.x) | ((uint)f2h(a.y) << 16);
    o.y = (uint)f2h(a.z) | ((uint)f2h(a.w) << 16);
    o.z = (uint)f2h(b.x) | ((uint)f2h(b.y) << 16);
    o.w = (uint)f2h(b.z) | ((uint)f2h(b.w) << 16);
    reinterpret_cast<uint4*>(outp)[i] = o;
}

// ---------------- SpMM 128-dim f16 gather: one wave per row, 2 dims/lane ----------------

__global__ __launch_bounds__(256) void spmm_f16_kernel(const int2* __restrict__ ep,
                                                       const int* __restrict__ row_ptr,
                                                       const uint* __restrict__ Xh,
                                                       float* __restrict__ out) {
    int wave = threadIdx.x >> 6;
    int lane = threadIdx.x & 63;
    int r = blockIdx.x * 4 + wave;
    if (r >= N_NODES) return;
    int beg = row_ptr[r];
    int end = row_ptr[r + 1];
    float a0x = 0.f, a0y = 0.f, a1x = 0.f, a1y = 0.f;
    int e = beg;
    for (; e + 7 < end; e += 8) {
        int2 cv[8];
        uint xu[8];
#pragma unroll
        for (int i = 0; i < 8; ++i) cv[i] = ep[e + i];
#pragma unroll
        for (int i = 0; i < 8; ++i) xu[i] = Xh[(size_t)cv[i].x * 64 + lane];
#pragma unroll
        for (int i = 0; i < 8; ++i) {
            float v = __int_as_float(cv[i].y);
            __half2 h2 = *reinterpret_cast<__half2*>(&xu[i]);
            float2 f = __half22float2(h2);
            if (i & 1) { a1x += v * f.x; a1y += v * f.y; }
            else       { a0x += v * f.x; a0y += v * f.y; }
        }
    }
    for (; e < end; ++e) {
        int2 cv = ep[e];
        float v = __int_as_float(cv.y);
        uint xu = Xh[(size_t)cv.x * 64 + lane];
        __half2 h2 = *reinterpret_cast<__half2*>(&xu);
        float2 f = __half22float2(h2);
        a0x += v * f.x;
        a0y += v * f.y;
    }
    float2 o = make_float2(a0x + a1x, a0y + a1y);
    *reinterpret_cast<float2*>(out + (size_t)r * DIM_IN + lane * 2) = o;
}

// ---------------- SpMM 64-dim f16 gather + tanh: one wave per row, 1 dim/lane ----------

__global__ __launch_bounds__(256) void spmm64_f16_tanh_kernel(const int2* __restrict__ ep,
                                                              const int* __restrict__ row_ptr,
                                                              const ushort* __restrict__ Ph,
                                                              float* __restrict__ out) {
    int wave = threadIdx.x >> 6;
    int lane = threadIdx.x & 63;
    int r = blockIdx.x * 4 + wave;
    if (r >= N_NODES) return;
    int beg = row_ptr[r];
    int end = row_ptr[r + 1];
    float acc0 = 0.f, acc1 = 0.f;
    int e = beg;
    for (; e + 7 < end; e += 8) {
        int2 cv[8];
        ushort xu[8];
#pragma unroll
        for (int i = 0; i < 8; ++i) cv[i] = ep[e + i];
#pragma unroll
        for (int i = 0; i < 8; ++i) xu[i] = Ph[(size_t)cv[i].x * 64 + lane];
#pragma unroll
        for (int i = 0; i < 8; ++i) {
            float v = __int_as_float(cv[i].y);
            __half h = *reinterpret_cast<__half*>(&xu[i]);
            float x = __half2float(h);
            if (i & 1) acc1 += v * x;
            else       acc0 += v * x;
        }
    }
    for (; e < end; ++e) {
        int2 cv = ep[e];
        ushort u = Ph[(size_t)cv.x * 64 + lane];
        __half h = *reinterpret_cast<__half*>(&u);
        acc0 += __int_as_float(cv.y) * __half2float(h);
    }
    out[(size_t)r * DIM_OUT + lane] = tanhf(acc0 + acc1);
}

// ---------------- GEMM: out[i,j] = (tanh?)(sum_k A[i,k] * W[j,k]) ----------------

template <int NOUT, bool TANH, bool F16OUT>
__global__ __launch_bounds__(256) void gemm_kernel(const float* __restrict__ A,
                                                   const float* __restrict__ W,
                                                   void* __restrict__ out_v, int M) {
    constexpr int CPT = NOUT / 16;  // 8 (layer1) or 4 (layer2)
    constexpr int BK = 32;
    __shared__ __align__(16) float sA[128 * BK];
    __shared__ __align__(16) float sW[NOUT * BK];

    const int t = threadIdx.x;
    const int tr = t & 15;
    const int tc = t >> 4;
    const int row0 = blockIdx.x * 128;

    float acc[8][CPT];
#pragma unroll
    for (int r = 0; r < 8; ++r)
#pragma unroll
        for (int c = 0; c < CPT; ++c) acc[r][c] = 0.f;

    for (int kb = 0; kb < DIM_IN / BK; ++kb) {
#pragma unroll
        for (int p = 0; p < 4; ++p) {
            int fid = p * 256 + t;
            int row = fid >> 3;
            int col4 = fid & 7;
            int gr = row0 + row;
            float4 v = make_float4(0.f, 0.f, 0.f, 0.f);
            if (gr < M) v = *reinterpret_cast<const float4*>(A + (size_t)gr * DIM_IN + kb * BK + col4 * 4);
            int sw = col4 ^ ((row >> 3) & 7);
            *reinterpret_cast<float4*>(sA + row * BK + sw * 4) = v;
        }
#pragma unroll
        for (int p = 0; p < NOUT / 32; ++p) {
            int fid = p * 256 + t;
            int row = fid >> 3;
            int col4 = fid & 7;
            float4 v = *reinterpret_cast<const float4*>(W + (size_t)row * DIM_IN + kb * BK + col4 * 4);
            int sw = col4 ^ ((row >> 3) & 7);
            *reinterpret_cast<float4*>(sW + row * BK + sw * 4) = v;
        }
        __syncthreads();
#pragma unroll
        for (int k4 = 0; k4 < 8; ++k4) {
            float4 a4[8];
            const int swa = (k4 ^ (tr & 7)) << 2;
#pragma unroll
            for (int r = 0; r < 8; ++r)
                a4[r] = *reinterpret_cast<const float4*>(sA + (tr * 8 + r) * BK + swa);
            float4 w4[CPT];
#pragma unroll
            for (int c = 0; c < CPT; ++c) {
                int wrow = tc * CPT + c;
                int sww = (k4 ^ ((wrow >> 3) & 7)) << 2;
                w4[c] = *reinterpret_cast<const float4*>(sW + wrow * BK + sww);
            }
#pragma unroll
            for (int r = 0; r < 8; ++r)
#pragma unroll
                for (int c = 0; c < CPT; ++c) {
                    acc[r][c] += a4[r].x * w4[c].x;
                    acc[r][c] += a4[r].y * w4[c].y;
                    acc[r][c] += a4[r].z * w4[c].z;
                    acc[r][c] += a4[r].w * w4[c].w;
                }
        }
        __syncthreads();
    }

#pragma unroll
    for (int r = 0; r < 8; ++r) {
        int gr = row0 + tr * 8 + r;
        if (gr >= M) continue;
        if (F16OUT) {
            ushort u[CPT];
#pragma unroll
            for (int c = 0; c < CPT; ++c)
                u[c] = f2h(TANH ? tanhf(acc[r][c]) : acc[r][c]);
            if (CPT == 4) {
                uint2 s;
                s.x = (uint)u[0] | ((uint)u[1] << 16);
                s.y = (uint)u[2] | ((uint)u[3] << 16);
                *reinterpret_cast<uint2*>((ushort*)out_v + (size_t)gr * NOUT + tc * CPT) = s;
            } else {
#pragma unroll
                for (int c = 0; c < CPT; ++c)
                    ((ushort*)out_v)[(size_t)gr * NOUT + tc * CPT + c] = u[c];
            }
        } else {
            float* out = (float*)out_v;
#pragma unroll
            for (int c4 = 0; c4 < CPT / 4; ++c4) {
                float4 v;
                v.x = TANH ? tanhf(acc[r][c4 * 4 + 0]) : acc[r][c4 * 4 + 0];
                v.y = TANH ? tanhf(acc[r][c4 * 4 + 1]) : acc[r][c4 * 4 + 1];
                v.z = TANH ? tanhf(acc[r][c4 * 4 + 2]) : acc[r][c4 * 4 + 2];
                v.w = TANH ? tanhf(acc[r][c4 * 4 + 3]) : acc[r][c4 * 4 + 3];
                *reinterpret_cast<float4*>(out + (size_t)gr * NOUT + tc * CPT + c4 * 4) = v;
            }
        }
    }
}

// ---------------- launch ----------------

extern "C" void kernel_launch(void* const* d_in, const int* in_sizes, int n_in,
                              void* d_out, int out_size, void* d_ws, size_t ws_size,
                              hipStream_t stream) {
    const float* X = (const float*)d_in[0];
    const float* W1 = (const float*)d_in[1];
    const float* W2 = (const float*)d_in[2];
    const float* evals = (const float*)d_in[3];
    const int* erow = (const int*)d_in[4];
    const int* ecol = (const int*)d_in[5];
    float* out = (float*)d_out;

    const int N = N_NODES;
    const int E = N_EDGES;

    char* ws = (char*)d_ws;
    size_t off = 0;
    auto alloc = [&](size_t bytes) {
        size_t o = off;
        off = (off + bytes + 255) & ~(size_t)255;
        return o;
    };
    size_t o_counts = alloc((size_t)NB * NCHUNK * 4);
    size_t o_offnb = alloc((size_t)NB * NCHUNK * 4);
    size_t o_tot = alloc((size_t)NB * 4);
    size_t o_bbase = alloc((size_t)(NB + 1) * 4);
    size_t o_rowptr = alloc((size_t)(N + 1) * 4);
    size_t o_ep = alloc((size_t)E * 8);
    size_t o_agg = alloc((size_t)N * DIM_IN * 4);  // agg f32; also hosts keyOut/valOut early, p f16 late
    size_t o_h = alloc((size_t)N * DIM_IN * 4);    // h f32; first hosts Xh f16
    (void)ws_size;

    int* counts = (int*)(ws + o_counts);
    int* offnb = (int*)(ws + o_offnb);
    int* tot = (int*)(ws + o_tot);
    int* bbase = (int*)(ws + o_bbase);
    int* row_ptr = (int*)(ws + o_rowptr);
    int2* ep = (int2*)(ws + o_ep);
    float* agg = (float*)(ws + o_agg);
    float* h = (float*)(ws + o_h);
    uint* Xh = (uint*)(ws + o_h);                       // [N,128] f16, dead before gemm1 writes h
    ushort* p = (ushort*)(ws + o_agg);                  // [N,64] f16, after gemm1 consumed agg
    uint* keyOut = (uint*)(ws + o_agg);                 // E*4, dead before spmm1 writes agg
    float* valOut = (float*)(ws + o_agg + (size_t)E * 4);  // E*4 (total 12.8MB << 51.2MB)

    // X -> f16 (independent; issue first)
    const int ncvt = N * DIM_IN / 8;
    cvt_f16_kernel<<<(ncvt + 255) / 256, 256, 0, stream>>>(X, Xh, ncvt);

    // CSR build (deterministic counting sort, no global atomics)
    chunk_hist_kernel<<<NCHUNK, 256, 0, stream>>>(erow, counts, E);
    bucket_scan_kernel<<<NB, 512, 0, stream>>>(counts, offnb, tot);
    base_scan_kernel<<<1, 512, 0, stream>>>(tot, bbase);
    coarse_scatter_kernel<<<NCHUNK, 512, 0, stream>>>(erow, ecol, evals, offnb, bbase,
                                                      keyOut, valOut, E);
    fine_sort_kernel<<<NB, 256, 0, stream>>>(keyOut, valOut, bbase, row_ptr, ep);

    const int spmm_grid = (N + 3) / 4;
    const int gemm_grid = (N + 127) / 128;

    // layer 1: agg = A*Xh ; h = tanh(agg @ W1^T)
    spmm_f16_kernel<<<spmm_grid, 256, 0, stream>>>(ep, row_ptr, Xh, agg);
    gemm_kernel<128, true, false><<<gemm_grid, 256, 0, stream>>>(agg, W1, h, N);
    // layer 2 (reordered): p = f16(h @ W2^T) ; out = tanh(A*p)
    gemm_kernel<64, false, true><<<gemm_grid, 256, 0, stream>>>(h, W2, p, N);
    spmm64_f16_tanh_kernel<<<spmm_grid, 256, 0, stream>>>(ep, row_ptr, p, out);
}

// Round 6
// 239.960 us; speedup vs baseline: 2.2015x; 1.3666x over previous
//
#include <hip/hip_runtime.h>
#include <hip/hip_bf16.h>
#include <hip/hip_fp16.h>

#define N_NODES 100000
#define N_EDGES 1600000
#define DIM_IN 128
#define DIM_OUT 64

#define NB 391      // coarse buckets: row >> 8 (256 rows each; last has 160)
#define NCHUNK 391  // edge chunks
#define CHUNK 4096  // edges per chunk (NCHUNK*CHUNK >= N_EDGES)
#define BCAP 5120   // max edges per bucket (mean 4092, sd ~64 -> +16 sigma)

typedef unsigned int uint;
typedef unsigned short ushort;
typedef _Float16 half8 __attribute__((ext_vector_type(8)));
typedef float f32x4 __attribute__((ext_vector_type(4)));

__device__ inline ushort f2h(float f) {
    __half h = __float2half(f);  // round-to-nearest-even
    return *reinterpret_cast<ushort*>(&h);
}

// ---------------- CSR build: deterministic two-level counting sort ----------------

__global__ __launch_bounds__(256) void chunk_hist_kernel(const int* __restrict__ erow,
                                                         int* __restrict__ counts, int E) {
    __shared__ int hist[NB];
    const int t = threadIdx.x, c = blockIdx.x;
    for (int b = t; b < NB; b += 256) hist[b] = 0;
    __syncthreads();
    const int eb = c * CHUNK;
#pragma unroll
    for (int i = 0; i < CHUNK / 256; ++i) {
        int e = eb + i * 256 + t;
        if (e < E) atomicAdd(&hist[erow[e] >> 8], 1);
    }
    __syncthreads();
    for (int b = t; b < NB; b += 256) counts[b * NCHUNK + c] = hist[b];
}

__global__ __launch_bounds__(512) void bucket_scan_kernel(const int* __restrict__ counts,
                                                          int* __restrict__ offnb,
                                                          int* __restrict__ tot) {
    __shared__ int s[512];
    const int b = blockIdx.x, t = threadIdx.x;
    int v = (t < NCHUNK) ? counts[b * NCHUNK + t] : 0;
    s[t] = v;
    __syncthreads();
#pragma unroll
    for (int o = 1; o < 512; o <<= 1) {
        int x = s[t];
        int y = (t >= o) ? s[t - o] : 0;
        __syncthreads();
        s[t] = x + y;
        __syncthreads();
    }
    if (t < NCHUNK) offnb[b * NCHUNK + t] = s[t] - v;
    if (t == 511) tot[b] = s[511];
}

__global__ __launch_bounds__(512) void base_scan_kernel(const int* __restrict__ tot,
                                                        int* __restrict__ bbase) {
    __shared__ int s[512];
    const int t = threadIdx.x;
    int v = (t < NB) ? tot[t] : 0;
    s[t] = v;
    __syncthreads();
#pragma unroll
    for (int o = 1; o < 512; o <<= 1) {
        int x = s[t];
        int y = (t >= o) ? s[t - o] : 0;
        __syncthreads();
        s[t] = x + y;
        __syncthreads();
    }
    if (t < NB) bbase[t] = s[t] - v;
    if (t == 511) bbase[NB] = s[511];
}

__global__ __launch_bounds__(512) void coarse_scatter_kernel(const int* __restrict__ erow,
                                                             const int* __restrict__ ecol,
                                                             const float* __restrict__ eval,
                                                             const int* __restrict__ offnb,
                                                             const int* __restrict__ bbase,
                                                             uint* __restrict__ keyOut,
                                                             float* __restrict__ valOut, int E) {
    __shared__ int hist[NB];
    __shared__ int segOff[NB];
    __shared__ int localOff[NB];
    __shared__ int sc[512];
    __shared__ int idxL[CHUNK];
    __shared__ int gaddrL[CHUNK];

    const int t = threadIdx.x, c = blockIdx.x;
    for (int b = t; b < NB; b += 512) {
        hist[b] = 0;
        segOff[b] = bbase[b] + offnb[b * NCHUNK + c];
    }
    __syncthreads();
    const int eb = c * CHUNK;
    uint bq[CHUNK / 512];
#pragma unroll
    for (int i = 0; i < CHUNK / 512; ++i) {
        int e = eb + i * 512 + t;
        if (e < E) {
            int b = erow[e] >> 8;
            int q = atomicAdd(&hist[b], 1);
            bq[i] = ((uint)b << 16) | (uint)q;
        } else {
            bq[i] = 0xFFFFFFFFu;
        }
    }
    __syncthreads();
    int v = (t < NB) ? hist[t] : 0;
    sc[t] = v;
    __syncthreads();
#pragma unroll
    for (int o = 1; o < 512; o <<= 1) {
        int x = sc[t];
        int y = (t >= o) ? sc[t - o] : 0;
        __syncthreads();
        sc[t] = x + y;
        __syncthreads();
    }
    if (t < NB) localOff[t] = sc[t] - v;
    __syncthreads();
#pragma unroll
    for (int i = 0; i < CHUNK / 512; ++i) {
        if (bq[i] != 0xFFFFFFFFu) {
            int b = bq[i] >> 16;
            int q = bq[i] & 0xFFFF;
            int s = localOff[b] + q;
            idxL[s] = eb + i * 512 + t;
            gaddrL[s] = segOff[b] + q;
        }
    }
    __syncthreads();
    const int m = min(CHUNK, E - eb);
    for (int s = t; s < m; s += 512) {
        int e = idxL[s];
        int g = gaddrL[s];
        keyOut[g] = ((uint)(erow[e] & 255) << 17) | (uint)ecol[e];
        valOut[g] = eval[e];
    }
}

__global__ __launch_bounds__(256) void fine_sort_kernel(const uint* __restrict__ keyOut,
                                                        const float* __restrict__ valOut,
                                                        const int* __restrict__ bbase,
                                                        int* __restrict__ row_ptr,
                                                        int2* __restrict__ ep) {
    __shared__ uint keyL[BCAP];
    __shared__ int hist[256];
    __shared__ int offs[256];
    const int b = blockIdx.x, t = threadIdx.x;
    const int s0 = bbase[b], s1 = bbase[b + 1];
    const int m = min(s1 - s0, BCAP);
    hist[t] = 0;
    __syncthreads();
    for (int j = t; j < m; j += 256) {
        uint k = keyOut[s0 + j];
        keyL[j] = k;
        atomicAdd(&hist[k >> 17], 1);
    }
    __syncthreads();
    int v = hist[t];
    offs[t] = v;
    __syncthreads();
#pragma unroll
    for (int o = 1; o < 256; o <<= 1) {
        int x = offs[t];
        int y = (t >= o) ? offs[t - o] : 0;
        __syncthreads();
        offs[t] = x + y;
        __syncthreads();
    }
    int excl = offs[t] - v;
    int row = b * 256 + t;
    if (row < N_NODES) row_ptr[row] = s0 + excl;
    if (b == NB - 1 && t == 0) row_ptr[N_NODES] = s1;
    hist[t] = excl;
    __syncthreads();
    for (int j = t; j < m; j += 256) {
        uint k = keyL[j];
        int pos = atomicAdd(&hist[k >> 17], 1);
        float vv = valOut[s0 + j];
        ep[s0 + pos] = make_int2((int)(k & 0x1FFFFu), __float_as_int(vv));
    }
}

// ---------------- f32 -> f16 conversion (8 elems/thread) ----------------

__global__ __launch_bounds__(256) void cvt_f16_kernel(const float* __restrict__ in,
                                                      uint* __restrict__ outp, int n8) {
    int i = blockIdx.x * 256 + threadIdx.x;
    if (i >= n8) return;
    const float4* in4 = reinterpret_cast<const float4*>(in) + (size_t)i * 2;
    float4 a = in4[0];
    float4 b = in4[1];
    uint4 o;
    o.x = (uint)f2h(a.x) | ((uint)f2h(a.y) << 16);
    o.y = (uint)f2h(a.z) | ((uint)f2h(a.w) << 16);
    o.z = (uint)f2h(b.x) | ((uint)f2h(b.y) << 16);
    o.w = (uint)f2h(b.z) | ((uint)f2h(b.w) << 16);
    reinterpret_cast<uint4*>(outp)[i] = o;
}

// ---------------- SpMM 128-dim f16 gather -> packed f16 out ----------------

__global__ __launch_bounds__(256) void spmm_f16_kernel(const int2* __restrict__ ep,
                                                       const int* __restrict__ row_ptr,
                                                       const uint* __restrict__ Xh,
                                                       uint* __restrict__ aggh) {
    int wave = threadIdx.x >> 6;
    int lane = threadIdx.x & 63;
    int r = blockIdx.x * 4 + wave;
    if (r >= N_NODES) return;
    int beg = row_ptr[r];
    int end = row_ptr[r + 1];
    float a0x = 0.f, a0y = 0.f, a1x = 0.f, a1y = 0.f;
    int e = beg;
    for (; e + 7 < end; e += 8) {
        int2 cv[8];
        uint xu[8];
#pragma unroll
        for (int i = 0; i < 8; ++i) cv[i] = ep[e + i];
#pragma unroll
        for (int i = 0; i < 8; ++i) xu[i] = Xh[(size_t)cv[i].x * 64 + lane];
#pragma unroll
        for (int i = 0; i < 8; ++i) {
            float v = __int_as_float(cv[i].y);
            __half2 h2 = *reinterpret_cast<__half2*>(&xu[i]);
            float2 f = __half22float2(h2);
            if (i & 1) { a1x += v * f.x; a1y += v * f.y; }
            else       { a0x += v * f.x; a0y += v * f.y; }
        }
    }
    for (; e < end; ++e) {
        int2 cv = ep[e];
        float v = __int_as_float(cv.y);
        uint xu = Xh[(size_t)cv.x * 64 + lane];
        __half2 h2 = *reinterpret_cast<__half2*>(&xu);
        float2 f = __half22float2(h2);
        a0x += v * f.x;
        a0y += v * f.y;
    }
    uint o = (uint)f2h(a0x + a1x) | ((uint)f2h(a0y + a1y) << 16);
    aggh[(size_t)r * 64 + lane] = o;
}

// ---------------- SpMM 64-dim f16 gather + tanh ----------------

__global__ __launch_bounds__(256) void spmm64_f16_tanh_kernel(const int2* __restrict__ ep,
                                                              const int* __restrict__ row_ptr,
                                                              const ushort* __restrict__ Ph,
                                                              float* __restrict__ out) {
    int wave = threadIdx.x >> 6;
    int lane = threadIdx.x & 63;
    int r = blockIdx.x * 4 + wave;
    if (r >= N_NODES) return;
    int beg = row_ptr[r];
    int end = row_ptr[r + 1];
    float acc0 = 0.f, acc1 = 0.f;
    int e = beg;
    for (; e + 7 < end; e += 8) {
        int2 cv[8];
        ushort xu[8];
#pragma unroll
        for (int i = 0; i < 8; ++i) cv[i] = ep[e + i];
#pragma unroll
        for (int i = 0; i < 8; ++i) xu[i] = Ph[(size_t)cv[i].x * 64 + lane];
#pragma unroll
        for (int i = 0; i < 8; ++i) {
            float v = __int_as_float(cv[i].y);
            __half h = *reinterpret_cast<__half*>(&xu[i]);
            float x = __half2float(h);
            if (i & 1) acc1 += v * x;
            else       acc0 += v * x;
        }
    }
    for (; e < end; ++e) {
        int2 cv = ep[e];
        ushort u = Ph[(size_t)cv.x * 64 + lane];
        __half h = *reinterpret_cast<__half*>(&u);
        acc0 += __int_as_float(cv.y) * __half2float(h);
    }
    out[(size_t)r * DIM_OUT + lane] = tanhf(acc0 + acc1);
}

// ---------------- Fused MLP: P = tanh(agg @ W1^T) @ W2^T, all f16 MFMA ----------------
// 128 rows/block, 256 threads = 4 waves; wave w owns rows w*32..w*32+31.
// LDS rows are 128 f16 (256B = 16 x 16B slots), slot XOR-swizzled by (row&7) so the
// 16-row fragment reads (ds_read_b128) spread across all 32 banks.
// mfma_f32_16x16x32_f16 fragments: A/B lane l: row/col = l&15, k = (l>>4)*8..+7;
// C/D lane l: col = l&15, row = (l>>4)*4 + reg.

__global__ __launch_bounds__(256) void fused_mlp_kernel(const uint* __restrict__ Ah,
                                                        const uint* __restrict__ W1h,
                                                        const uint* __restrict__ W2h,
                                                        uint* __restrict__ Ph, int M) {
    __shared__ __align__(16) ushort sA[128 * 128];   // agg tile, then H
    __shared__ __align__(16) ushort sW1[128 * 128];  // W1, then P (16KB used)
    __shared__ __align__(16) ushort sW2[64 * 128];

    const int t = threadIdx.x;
    const int l = t & 63;
    const int w = t >> 6;
    const int row0 = blockIdx.x * 128;
    const int lr = l & 15;
    const int lk = l >> 4;

    // ---- stage agg / W1 / W2 (uint4 = 16B slots, swizzled) ----
#pragma unroll
    for (int i = 0; i < 8; ++i) {
        int fid = i * 256 + t;
        int row = fid >> 4, slot = fid & 15;
        int gr = row0 + row;
        uint4 v = make_uint4(0, 0, 0, 0);
        if (gr < M) v = reinterpret_cast<const uint4*>(Ah)[(size_t)gr * 16 + slot];
        *reinterpret_cast<uint4*>(&sA[row * 128 + ((slot ^ (row & 7)) << 3)]) = v;
    }
#pragma unroll
    for (int i = 0; i < 8; ++i) {
        int fid = i * 256 + t;
        int row = fid >> 4, slot = fid & 15;
        uint4 v = reinterpret_cast<const uint4*>(W1h)[row * 16 + slot];
        *reinterpret_cast<uint4*>(&sW1[row * 128 + ((slot ^ (row & 7)) << 3)]) = v;
    }
#pragma unroll
    for (int i = 0; i < 4; ++i) {
        int fid = i * 256 + t;
        int row = fid >> 4, slot = fid & 15;
        uint4 v = reinterpret_cast<const uint4*>(W2h)[row * 16 + slot];
        *reinterpret_cast<uint4*>(&sW2[row * 128 + ((slot ^ (row & 7)) << 3)]) = v;
    }
    __syncthreads();

    // ---- stage 1: H = tanh(agg @ W1^T) ----
    f32x4 acc[2][8];
#pragma unroll
    for (int rf = 0; rf < 2; ++rf)
#pragma unroll
        for (int cf = 0; cf < 8; ++cf) acc[rf][cf] = (f32x4){0.f, 0.f, 0.f, 0.f};

    half8 aF[2][4];
#pragma unroll
    for (int rf = 0; rf < 2; ++rf) {
        int row = w * 32 + rf * 16 + lr;
#pragma unroll
        for (int kc = 0; kc < 4; ++kc) {
            int slot = kc * 4 + lk;
            aF[rf][kc] = *reinterpret_cast<const half8*>(&sA[row * 128 + ((slot ^ (row & 7)) << 3)]);
        }
    }
#pragma unroll
    for (int cf = 0; cf < 8; ++cf) {
        int col = cf * 16 + lr;
#pragma unroll
        for (int kc = 0; kc < 4; ++kc) {
            int slot = kc * 4 + lk;
            half8 bF = *reinterpret_cast<const half8*>(&sW1[col * 128 + ((slot ^ (col & 7)) << 3)]);
            acc[0][cf] = __builtin_amdgcn_mfma_f32_16x16x32_f16(aF[0][kc], bF, acc[0][cf], 0, 0, 0);
            acc[1][cf] = __builtin_amdgcn_mfma_f32_16x16x32_f16(aF[1][kc], bF, acc[1][cf], 0, 0, 0);
        }
    }
    __syncthreads();  // all sA reads done before overwrite with H

    // tanh + write H (f16, swizzled) into sA region
#pragma unroll
    for (int rf = 0; rf < 2; ++rf)
#pragma unroll
        for (int cf = 0; cf < 8; ++cf)
#pragma unroll
            for (int reg = 0; reg < 4; ++reg) {
                int row = w * 32 + rf * 16 + lk * 4 + reg;
                int col = cf * 16 + lr;
                sA[row * 128 + (((col >> 3) ^ (row & 7)) << 3) + (col & 7)] =
                    f2h(tanhf(acc[rf][cf][reg]));
            }
    __syncthreads();

    // ---- stage 2: P = H @ W2^T ----
    f32x4 acc2[2][4];
#pragma unroll
    for (int rf = 0; rf < 2; ++rf)
#pragma unroll
        for (int cf = 0; cf < 4; ++cf) acc2[rf][cf] = (f32x4){0.f, 0.f, 0.f, 0.f};
#pragma unroll
    for (int rf = 0; rf < 2; ++rf) {
        int row = w * 32 + rf * 16 + lr;
#pragma unroll
        for (int kc = 0; kc < 4; ++kc) {
            int slot = kc * 4 + lk;
            aF[rf][kc] = *reinterpret_cast<const half8*>(&sA[row * 128 + ((slot ^ (row & 7)) << 3)]);
        }
    }
#pragma unroll
    for (int cf = 0; cf < 4; ++cf) {
        int col = cf * 16 + lr;
#pragma unroll
        for (int kc = 0; kc < 4; ++kc) {
            int slot = kc * 4 + lk;
            half8 bF = *reinterpret_cast<const half8*>(&sW2[col * 128 + ((slot ^ (col & 7)) << 3)]);
            acc2[0][cf] = __builtin_amdgcn_mfma_f32_16x16x32_f16(aF[0][kc], bF, acc2[0][cf], 0, 0, 0);
            acc2[1][cf] = __builtin_amdgcn_mfma_f32_16x16x32_f16(aF[1][kc], bF, acc2[1][cf], 0, 0, 0);
        }
    }

    // write P (plain row-major f16) into sW1 region (dead since stage 1)
    ushort* sP = sW1;  // 128 rows x 64 ushorts
#pragma unroll
    for (int rf = 0; rf < 2; ++rf)
#pragma unroll
        for (int cf = 0; cf < 4; ++cf)
#pragma unroll
            for (int reg = 0; reg < 4; ++reg) {
                int row = w * 32 + rf * 16 + lk * 4 + reg;
                int col = cf * 16 + lr;
                sP[row * 64 + col] = f2h(acc2[rf][cf][reg]);
            }
    __syncthreads();

    // coalesced copy-out
#pragma unroll
    for (int i = 0; i < 4; ++i) {
        int fid = i * 256 + t;
        int row = fid >> 3, q = fid & 7;
        int gr = row0 + row;
        if (gr < M)
            reinterpret_cast<uint4*>(Ph)[(size_t)gr * 8 + q] =
                *reinterpret_cast<const uint4*>(&sP[row * 64 + q * 8]);
    }
}

// ---------------- launch ----------------

extern "C" void kernel_launch(void* const* d_in, const int* in_sizes, int n_in,
                              void* d_out, int out_size, void* d_ws, size_t ws_size,
                              hipStream_t stream) {
    const float* X = (const float*)d_in[0];
    const float* W1 = (const float*)d_in[1];
    const float* W2 = (const float*)d_in[2];
    const float* evals = (const float*)d_in[3];
    const int* erow = (const int*)d_in[4];
    const int* ecol = (const int*)d_in[5];
    float* out = (float*)d_out;

    const int N = N_NODES;
    const int E = N_EDGES;

    char* ws = (char*)d_ws;
    size_t off = 0;
    auto alloc = [&](size_t bytes) {
        size_t o = off;
        off = (off + bytes + 255) & ~(size_t)255;
        return o;
    };
    size_t o_counts = alloc((size_t)NB * NCHUNK * 4);
    size_t o_offnb = alloc((size_t)NB * NCHUNK * 4);
    size_t o_tot = alloc((size_t)NB * 4);
    size_t o_bbase = alloc((size_t)(NB + 1) * 4);
    size_t o_rowptr = alloc((size_t)(N + 1) * 4);
    size_t o_ep = alloc((size_t)E * 8);
    size_t o_agg = alloc((size_t)N * 64 * 4);  // aggh [N][64] uint; hosts keyOut/valOut first
    size_t o_xh = alloc((size_t)N * 64 * 4);   // Xh [N][64] uint
    size_t o_p = alloc((size_t)N * 32 * 4);    // Ph [N][32] uint
    size_t o_w1h = alloc((size_t)128 * 64 * 4);
    size_t o_w2h = alloc((size_t)64 * 64 * 4);
    (void)ws_size;

    int* counts = (int*)(ws + o_counts);
    int* offnb = (int*)(ws + o_offnb);
    int* tot = (int*)(ws + o_tot);
    int* bbase = (int*)(ws + o_bbase);
    int* row_ptr = (int*)(ws + o_rowptr);
    int2* ep = (int2*)(ws + o_ep);
    uint* aggh = (uint*)(ws + o_agg);
    uint* Xh = (uint*)(ws + o_xh);
    uint* Ph = (uint*)(ws + o_p);
    uint* W1h = (uint*)(ws + o_w1h);
    uint* W2h = (uint*)(ws + o_w2h);
    uint* keyOut = (uint*)(ws + o_agg);                    // dead before spmm1 writes aggh
    float* valOut = (float*)(ws + o_agg + (size_t)E * 4);  // E*8 total <= 25.6MB region

    // conversions (independent; issue first)
    const int ncvt = N * DIM_IN / 8;
    cvt_f16_kernel<<<(ncvt + 255) / 256, 256, 0, stream>>>(X, Xh, ncvt);
    cvt_f16_kernel<<<8, 256, 0, stream>>>(W1, W1h, 128 * 128 / 8);
    cvt_f16_kernel<<<4, 256, 0, stream>>>(W2, W2h, 64 * 128 / 8);

    // CSR build (deterministic counting sort, no global atomics)
    chunk_hist_kernel<<<NCHUNK, 256, 0, stream>>>(erow, counts, E);
    bucket_scan_kernel<<<NB, 512, 0, stream>>>(counts, offnb, tot);
    base_scan_kernel<<<1, 512, 0, stream>>>(tot, bbase);
    coarse_scatter_kernel<<<NCHUNK, 512, 0, stream>>>(erow, ecol, evals, offnb, bbase,
                                                      keyOut, valOut, E);
    fine_sort_kernel<<<NB, 256, 0, stream>>>(keyOut, valOut, bbase, row_ptr, ep);

    const int spmm_grid = (N + 3) / 4;
    const int mlp_grid = (N + 127) / 128;

    // layer 1 spmm: aggh = f16(A * Xh)
    spmm_f16_kernel<<<spmm_grid, 256, 0, stream>>>(ep, row_ptr, Xh, aggh);
    // fused MLP: Ph = f16( tanh(aggh @ W1^T) @ W2^T )
    fused_mlp_kernel<<<mlp_grid, 256, 0, stream>>>(aggh, W1h, W2h, Ph, N);
    // layer 2 spmm + tanh: out = tanh(A * Ph)
    spmm64_f16_tanh_kernel<<<spmm_grid, 256, 0, stream>>>(ep, row_ptr, (const ushort*)Ph, out);
}